// Round 13
// baseline (1339.345 us; speedup 1.0000x reference)
//
#include <hip/hip_runtime.h>
#include <math.h>

#define N_PTS 120000
#define M_PTS 30000
#define NCHUNK 469               // style: 469 * 64 rows = 30016 (padded)
#define NCH32 938                // k_net: 938 * 32 rows = 30016
#define TS (1 << 17)
#define TSM (TS - 1)
#define SCH 256                  // select chunk
#define NSCH 469                 // ceil(120000/256)

typedef __attribute__((ext_vector_type(8))) short bf16x8_t;
typedef __attribute__((ext_vector_type(4))) float f32x4_t;

// ---------------- workspace layout (bytes) ----------------
#define OFF_KEY    0ull                   // 4*TS*8  = 4194304
#define OFF_CNT    4194304ull             // 4*TS*4  = 2097152
#define OFF_SUM    6291456ull             // 2097152
#define OFF_SEL    8388608ull             // 4*120000*4 = 1920000
#define OFF_AUX    10308608ull            // 256
#define OFF_DOWN   10308864ull            // 4*30000*3*4 = 1440000
#define OFF_GENC   11748864ull            // 2048
#define OFF_STYLE  11750912ull            // 2048
#define OFF_TESF   11752960ull            // 2048
#define OFF_PSEW2  11755008ull            // 16384
#define OFF_PSEW3  11771392ull            // 65536
#define OFF_PPEW2  11836928ull            // 65536
#define OFF_PPEW3  11902464ull            // 131072
#define OFF_POW1   12033536ull            // 131072
#define OFF_POW2   12164608ull            // 65536
#define OFF_PLW1   12230144ull            // 1572864
#define OFF_PLW2   13803008ull            // 1572864
#define OFF_SCNT   15375872ull            // 4*469*4 = 7504
#define OFF_KTOT   15383552ull            // 16
#define WS_NEED    15383568ull

struct Aux {
  unsigned mn_enc[3];
  unsigned mx_enc[3];
  unsigned pad[10];   // -> 64 B
};

__device__ __forceinline__ unsigned encf(float v) {
  unsigned u = __float_as_uint(v);
  return (u & 0x80000000u) ? ~u : (u | 0x80000000u);
}
__device__ __forceinline__ float decf(unsigned u) {
  unsigned v = (u & 0x80000000u) ? (u & 0x7fffffffu) : ~u;
  return __uint_as_float(v);
}
__device__ __forceinline__ unsigned short f2bf(float f) {
  unsigned u = __float_as_uint(f);
  u += 0x7fffu + ((u >> 16) & 1u);
  return (unsigned short)(u >> 16);
}
// XOR-swizzled address into a bf16 tile with row stride RS bytes
template <int RS>
__device__ __forceinline__ unsigned swzad(int r, int c) {
  return ((unsigned)(r * RS + c * 2)) ^ ((unsigned)(r & 7) << 4);
}
template <int RS>
__device__ __forceinline__ void sth(unsigned short* B, int r, int c, unsigned short v) {
  *(unsigned short*)((char*)B + swzad<RS>(r, c)) = v;
}
template <int RS>
__device__ __forceinline__ float ldbf(const unsigned short* B, int r, int c) {
  unsigned short u = *(const unsigned short*)((const char*)B + swzad<RS>(r, c));
  return __uint_as_float((unsigned)u << 16);
}

// ---------------- downsample kernels (4 clouds in parallel) ----------------

__global__ void k_init(unsigned long long* __restrict__ key, int* __restrict__ cnt,
                       int* __restrict__ sum, int* __restrict__ sel, Aux* aux,
                       unsigned* __restrict__ genc) {
  int i = blockIdx.x * blockDim.x + threadIdx.x;
  if (i < 4 * TS) { key[i] = 0ull; cnt[i] = 0; sum[i] = 0; }
  if (i < 4 * N_PTS) sel[i] = 0;
  if (i < 12) { aux[i / 3].mn_enc[i % 3] = 0xFFFFFFFFu; aux[i / 3].mx_enc[i % 3] = 0u; }
  if (i < 512) genc[i] = 0u;
}

__device__ __forceinline__ const float* cloud_ptr(const float* noisy, const float* cond, int c) {
  return ((c & 1) ? noisy : cond) + (size_t)(c >> 1) * N_PTS * 3;
}

__global__ void k_minmax(const float* __restrict__ noisy, const float* __restrict__ cond,
                         Aux* aux) {
  __shared__ unsigned smn[3], smx[3];
  int t = threadIdx.x, c = blockIdx.y;
  const float* pts = cloud_ptr(noisy, cond, c);
  if (t < 3) { smn[t] = 0xFFFFFFFFu; smx[t] = 0u; }
  __syncthreads();
  unsigned lmn[3] = {0xFFFFFFFFu, 0xFFFFFFFFu, 0xFFFFFFFFu};
  unsigned lmx[3] = {0u, 0u, 0u};
  for (int i = blockIdx.x * blockDim.x + t; i < N_PTS; i += gridDim.x * blockDim.x) {
    #pragma unroll
    for (int k = 0; k < 3; k++) {
      unsigned e = encf(pts[i * 3 + k]);
      lmn[k] = min(lmn[k], e);
      lmx[k] = max(lmx[k], e);
    }
  }
  #pragma unroll
  for (int k = 0; k < 3; k++) { atomicMin(&smn[k], lmn[k]); atomicMax(&smx[k], lmx[k]); }
  __syncthreads();
  if (t < 3) { atomicMin(&aux[c].mn_enc[t], smn[t]); atomicMax(&aux[c].mx_enc[t], smx[t]); }
}

// vs computed per block from aux encodings (k_vs folded in)
__global__ void k_build(const float* __restrict__ noisy, const float* __restrict__ cond,
                        const Aux* __restrict__ aux, unsigned long long* __restrict__ keyg,
                        int* __restrict__ cntg, int* __restrict__ sumg) {
  __shared__ float smn[3];
  __shared__ double svs;
  int i = blockIdx.x * blockDim.x + threadIdx.x;
  int c = blockIdx.y;
  if (threadIdx.x == 0) {
    double prod = 1.0;
    for (int k = 0; k < 3; k++) {
      float mnf = decf(aux[c].mn_enc[k]);
      float mxf = decf(aux[c].mx_enc[k]);
      smn[k] = mnf;
      double r = (double)mxf - (double)mnf;
      if (r < 1e-6) r = 1.0;
      prod *= r;
    }
    double vs = pow(prod / (double)M_PTS, 1.0 / 3.0) * 1.2;
    if (vs < 1e-6) vs = 0.001;
    svs = vs;
  }
  __syncthreads();
  if (i >= N_PTS) return;
  const float* pts = cloud_ptr(noisy, cond, c);
  unsigned long long* key = keyg + (size_t)c * TS;
  int* cnt = cntg + (size_t)c * TS;
  int* sum = sumg + (size_t)c * TS;
  double vs = svs;
  unsigned h = 0u;
  const unsigned mulc[3] = {73856093u, 19349663u, 83492791u};
  #pragma unroll
  for (int k = 0; k < 3; k++) {
    int vi = (int)floor(((double)pts[i * 3 + k] - (double)smn[k]) / vs);
    h ^= (unsigned)vi * mulc[k];
  }
  unsigned long long want = 0x100000000ull | (unsigned long long)h;
  unsigned slot = (h * 2654435761u) >> 15;   // top 17 bits
  for (;;) {
    unsigned long long cur = key[slot];
    if (cur == want) break;
    if (cur == 0ull) {
      unsigned long long prev = atomicCAS(&key[slot], 0ull, want);
      if (prev == 0ull || prev == want) break;
    }
    slot = (slot + 1) & TSM;
  }
  atomicAdd(&cnt[slot], 1);
  atomicAdd(&sum[slot], i);
}

__global__ void k_reps(const unsigned long long* __restrict__ keyg, const int* __restrict__ cntg,
                       const int* __restrict__ sumg, int* __restrict__ selg) {
  int s = blockIdx.x * blockDim.x + threadIdx.x;
  int c = blockIdx.y;
  if (s >= TS) return;
  if (keyg[(size_t)c * TS + s] != 0ull) {
    int rep = sumg[(size_t)c * TS + s] / cntg[(size_t)c * TS + s];
    selg[(size_t)c * N_PTS + rep] = 1;
  }
}

// ---- 3-phase parallel stable select ----
__global__ void k_sel_cnt(const int* __restrict__ selg, int* __restrict__ scnt) {
  __shared__ int ws[4];
  int c = blockIdx.y, chunk = blockIdx.x, t = threadIdx.x;
  int i = chunk * SCH + t;
  int v = (i < N_PTS) ? selg[(size_t)c * N_PTS + i] : 0;
  int lane = t & 63, wid = t >> 6;
  int s = v;
  for (int d = 32; d; d >>= 1) s += __shfl_down(s, d, 64);
  if (lane == 0) ws[wid] = s;
  __syncthreads();
  if (t == 0) scnt[c * NSCH + chunk] = ws[0] + ws[1] + ws[2] + ws[3];
}

__global__ void k_sel_scan(int* __restrict__ scnt, int* __restrict__ ktot) {
  __shared__ int buf[512];
  int c = blockIdx.x, t = threadIdx.x;
  int v = (t < NSCH) ? scnt[c * NSCH + t] : 0;
  buf[t] = v;
  __syncthreads();
  for (int d = 1; d < 512; d <<= 1) {
    int x = (t >= d) ? buf[t - d] : 0;
    __syncthreads();
    buf[t] += x;
    __syncthreads();
  }
  if (t < NSCH) scnt[c * NSCH + t] = buf[t] - v;   // exclusive
  if (t == NSCH - 1) ktot[c] = buf[t];
}

__global__ void k_sel_gather(const int* __restrict__ selg, const int* __restrict__ scnt,
                             const int* __restrict__ ktot,
                             const float* __restrict__ noisy, const float* __restrict__ cond,
                             float* __restrict__ downg, float* __restrict__ idxbase) {
  __shared__ int wbase[4];
  int c = blockIdx.y, chunk = blockIdx.x, t = threadIdx.x;
  int i = chunk * SCH + t;
  int v = (i < N_PTS) ? selg[(size_t)c * N_PTS + i] : 0;
  int lane = t & 63, wid = t >> 6;
  int incl = v;
  for (int d = 1; d < 64; d <<= 1) {
    int x = __shfl_up(incl, d, 64);
    if (lane >= d) incl += x;
  }
  if (lane == 63) wbase[wid] = incl;
  __syncthreads();
  int wb = 0;
  for (int k = 0; k < wid; k++) wb += wbase[k];
  int selBefore = scnt[c * NSCH + chunk] + wb + incl - v;
  if (i >= N_PTS) return;
  int slot = v ? selBefore : (ktot[c] + i - selBefore);
  if (slot < M_PTS) {
    const float* pts = cloud_ptr(noisy, cond, c);
    float* down = downg + (size_t)c * M_PTS * 3;
    down[slot * 3 + 0] = pts[i * 3 + 0];
    down[slot * 3 + 1] = pts[i * 3 + 1];
    down[slot * 3 + 2] = pts[i * 3 + 2];
    if (c & 1) idxbase[(size_t)(c >> 1) * M_PTS + slot] = (float)i;
  }
}

// ---------------- fused weight packing into MFMA B-frag order ----------------
__device__ __forceinline__ void pack_one(const float* __restrict__ W,
                                         unsigned short* __restrict__ dst,
                                         int KS, int NT, int idx) {
  int lane = idx & 63;
  int rest = idx >> 6;
  int nt = rest % NT; rest /= NT;
  int ks = rest % KS;
  int l = rest / KS;
  int N = NT * 16, K = KS * 32;
  const float* src = W + (size_t)l * K * N;
  int cc = nt * 16 + (lane & 15);
  int k0 = ks * 32 + ((lane >> 4) << 3);
  unsigned short* d = dst + (size_t)idx * 8;
  #pragma unroll
  for (int j = 0; j < 8; j++) d[j] = f2bf(src[(size_t)(k0 + j) * N + cc]);
}

__global__ void k_pack_all(
    const float* __restrict__ se_w2, const float* __restrict__ se_w3,
    const float* __restrict__ pe_w2, const float* __restrict__ pe_w3,
    const float* __restrict__ ow1, const float* __restrict__ ow2,
    const float* __restrict__ lw1, const float* __restrict__ lw2,
    unsigned short* __restrict__ psew2, unsigned short* __restrict__ psew3,
    unsigned short* __restrict__ ppew2, unsigned short* __restrict__ ppew3,
    unsigned short* __restrict__ pow1, unsigned short* __restrict__ pow2,
    unsigned short* __restrict__ plw1, unsigned short* __restrict__ plw2) {
  int blk = blockIdx.x;
  const float* W; unsigned short* D; int KS, NT, base;
  if (blk < 4)        { W = se_w2; D = psew2; KS = 2;  NT = 8;  base = 0; }
  else if (blk < 20)  { W = se_w3; D = psew3; KS = 4;  NT = 16; base = 4; }
  else if (blk < 36)  { W = pe_w2; D = ppew2; KS = 4;  NT = 16; base = 20; }
  else if (blk < 68)  { W = pe_w3; D = ppew3; KS = 8;  NT = 16; base = 36; }
  else if (blk < 100) { W = ow1;   D = pow1;  KS = 8;  NT = 16; base = 68; }
  else if (blk < 116) { W = ow2;   D = pow2;  KS = 8;  NT = 8;  base = 100; }
  else if (blk < 500) { W = lw1;   D = plw1;  KS = 8;  NT = 32; base = 116; }
  else                { W = lw2;   D = plw2;  KS = 16; NT = 16; base = 500; }
  pack_one(W, D, KS, NT, (blk - base) * 256 + threadIdx.x);
}

// ---------------- MFMA core (no prefetch, NTW<=2 register-proven) ----------------
template <int KS, int NTW, int MT, int RS>
__device__ __forceinline__ void mmW(const unsigned short* __restrict__ Bp,
                                    int kt0, int nt0, int NT,
                                    const unsigned short* __restrict__ A, int acb,
                                    int lane, f32x4_t (&acc)[MT][NTW]) {
  const int lr = lane & 15, lg = lane >> 4;
  #pragma unroll
  for (int ks = 0; ks < KS; ks++) {
    bf16x8_t af[MT];
    #pragma unroll
    for (int mt = 0; mt < MT; mt++)
      af[mt] = *(const bf16x8_t*)((const char*)A + swzad<RS>(mt * 16 + lr, acb + ks * 32 + lg * 8));
    #pragma unroll
    for (int n = 0; n < NTW; n++) {
      bf16x8_t b = *(const bf16x8_t*)(Bp + ((size_t)((kt0 + ks) * NT + nt0 + n) * 64 + lane) * 8);
      #pragma unroll
      for (int mt = 0; mt < MT; mt++)
        acc[mt][n] = __builtin_amdgcn_mfma_f32_16x16x32_bf16(af[mt], b, acc[mt][n], 0, 0, 0);
    }
  }
}

// ---------------- style encoder (per-point MLP + max pool) ----------------
__global__ __launch_bounds__(512, 2) void k_style2(
    const float* __restrict__ downg,
    const float* __restrict__ se_w1, const float* __restrict__ se_b1,
    const unsigned short* __restrict__ w2p, const float* __restrict__ se_b2,
    const unsigned short* __restrict__ w3p, const float* __restrict__ se_b3,
    unsigned* __restrict__ genc) {
  __shared__ __attribute__((aligned(16))) unsigned short Hs[64 * 256];
  const int t = threadIdx.x, lane = t & 63, w = t >> 6;
  const int lr = lane & 15, lg = lane >> 4;
  const int bt = blockIdx.y;
  const int row0 = blockIdx.x * 64;
  const float* downC = downg + (size_t)(bt << 1) * M_PTS * 3;
  {
    int r = t & 63, grow = row0 + r;
    float px = 0.f, py = 0.f, pz = 0.f;
    if (grow < M_PTS) { px = downC[grow * 3]; py = downC[grow * 3 + 1]; pz = downC[grow * 3 + 2]; }
    int c0 = (t >> 6) * 8;
    for (int i = 0; i < 8; i++) {
      int c = c0 + i;
      float v = fmaxf(se_b1[c] + px * se_w1[c] + py * se_w1[64 + c] + pz * se_w1[128 + c], 0.f);
      sth<512>(Hs, r, c, f2bf(v));
    }
  }
  __syncthreads();
  {
    f32x4_t acc[4][1];
    #pragma unroll
    for (int mt = 0; mt < 4; mt++) acc[mt][0] = 0.f;
    mmW<2, 1, 4, 512>(w2p, 0, w, 8, Hs, 0, lane, acc);
    int col = w * 16 + lr;
    float bb = se_b2[col];
    #pragma unroll
    for (int mt = 0; mt < 4; mt++)
      #pragma unroll
      for (int q = 0; q < 4; q++)
        sth<512>(Hs, mt * 16 + lg * 4 + q, 128 + col, f2bf(fmaxf(acc[mt][0][q] + bb, 0.f)));
  }
  __syncthreads();
  {
    f32x4_t acc[4][2];
    #pragma unroll
    for (int mt = 0; mt < 4; mt++) { acc[mt][0] = 0.f; acc[mt][1] = 0.f; }
    mmW<4, 2, 4, 512>(w3p, 0, w * 2, 16, Hs, 128, lane, acc);
    #pragma unroll
    for (int ntl = 0; ntl < 2; ntl++) {
      int col = (w * 2 + ntl) * 16 + lr;
      float bb = se_b3[col];
      float m = -3.4e38f;
      #pragma unroll
      for (int mt = 0; mt < 4; mt++)
        #pragma unroll
        for (int q = 0; q < 4; q++) {
          int grow = row0 + mt * 16 + lg * 4 + q;
          float v = acc[mt][ntl][q] + bb;
          if (grow < M_PTS) m = fmaxf(m, v);
        }
      m = fmaxf(m, __shfl_xor(m, 16, 64));
      m = fmaxf(m, __shfl_xor(m, 32, 64));
      if (lg == 0) atomicMax(&genc[bt * 256 + col], encf(m));
    }
  }
}

// style MLP + time/style projection, fused; grid 2, 512 thr
__global__ void k_smt(const unsigned* __restrict__ genc,
                      const float* __restrict__ w1, const float* __restrict__ b1,
                      const float* __restrict__ w2, const float* __restrict__ b2,
                      const int* __restrict__ tstep,
                      const float* __restrict__ tpw, const float* __restrict__ tpb,
                      const float* __restrict__ spw, const float* __restrict__ spb,
                      float* __restrict__ tesf2) {
  __shared__ float g[256], s1[512], st[256], te[128];
  int t = threadIdx.x, b = blockIdx.x;
  if (t < 256) g[t] = decf(genc[b * 256 + t]);
  __syncthreads();
  float h = b1[t];
  for (int k = 0; k < 256; k++) h += g[k] * w1[k * 512 + t];
  s1[t] = fmaxf(h, 0.f);
  __syncthreads();
  if (t < 256) {
    float o = b2[t];
    for (int k = 0; k < 512; k++) o += s1[k] * w2[k * 256 + t];
    st[t] = fmaxf(o, 0.f);
  }
  if (t < 64) {
    const float cfr = (float)(-9.210340371976184 / 63.0);
    float fr = expf((float)t * cfr);
    float ang = (float)tstep[b] * fr;
    te[t] = sinf(ang);
    te[64 + t] = cosf(ang);
  }
  __syncthreads();
  if (t < 256) {
    float v = tpb[t];
    for (int k = 0; k < 128; k++) v += te[k] * tpw[k * 256 + t];
    float v2 = spb[t];
    for (int k = 0; k < 256; k++) v2 += st[k] * spw[k * 256 + t];
    tesf2[b * 256 + t] = v + v2;
  }
}

// ---------------- fused per-point network: pe -> 6x residual -> out head ----------------
// 32 rows/block, 4 waves (MT=2, NTW=2, sequential passes), 48KB LDS -> 3 blocks/CU.
// launch_bounds(256,2) -> 128 VGPR cap; peak live ~75 regs -> no spill, no throttle.
__global__ __launch_bounds__(256, 2) void k_net(
    const float* __restrict__ downg, const float* __restrict__ tesf2,
    const float* __restrict__ pe_w1, const float* __restrict__ pe_b1,
    const unsigned short* __restrict__ pw2, const float* __restrict__ pe_b2,
    const unsigned short* __restrict__ pw3, const float* __restrict__ pe_b3,
    const unsigned short* __restrict__ w1p, const float* __restrict__ lb1,
    const unsigned short* __restrict__ w2p, const float* __restrict__ lb2,
    const unsigned short* __restrict__ o1p, const float* __restrict__ ob1,
    const unsigned short* __restrict__ o2p, const float* __restrict__ ob2,
    const float* __restrict__ ow3, const float* __restrict__ ob3,
    float* __restrict__ pred) {
  __shared__ __attribute__((aligned(16))) unsigned short Xb[32 * 256];  // 16 KB
  __shared__ __attribute__((aligned(16))) unsigned short Hb[32 * 512];  // 32 KB
  const int t = threadIdx.x, lane = t & 63, w = t >> 6;   // 4 waves
  const int lr = lane & 15, lg = lane >> 4;
  const int bt = blockIdx.y;
  const int row0 = blockIdx.x * 32;
  const float* dn = downg + (size_t)((bt << 1) | 1) * M_PTS * 3;
  const float* tesf = tesf2 + bt * 256;

  // pe L1: 3 -> 128 relu -> Hb cols [0,128)
  {
    int r = t & 31, grow = row0 + r;
    float px = 0.f, py = 0.f, pz = 0.f;
    if (grow < M_PTS) { px = dn[grow * 3]; py = dn[grow * 3 + 1]; pz = dn[grow * 3 + 2]; }
    int c0 = (t >> 5) * 16;
    for (int i = 0; i < 16; i++) {
      int c = c0 + i;
      float v = fmaxf(pe_b1[c] + px * pe_w1[c] + py * pe_w1[128 + c] + pz * pe_w1[256 + c], 0.f);
      sth<1024>(Hb, r, c, f2bf(v));
    }
  }
  __syncthreads();
  // pe L2: K=128 (Hb) -> 256 relu -> Xb  (NT=16, 2 passes x NTW=2)
  for (int pass = 0; pass < 2; pass++) {
    f32x4_t acc[2][2];
    #pragma unroll
    for (int mt = 0; mt < 2; mt++) { acc[mt][0] = 0.f; acc[mt][1] = 0.f; }
    mmW<4, 2, 2, 1024>(pw2, 0, pass * 8 + w * 2, 16, Hb, 0, lane, acc);
    #pragma unroll
    for (int ntl = 0; ntl < 2; ntl++) {
      int col = (pass * 8 + w * 2 + ntl) * 16 + lr;
      float bb = pe_b2[col];
      #pragma unroll
      for (int mt = 0; mt < 2; mt++)
        #pragma unroll
        for (int q = 0; q < 4; q++)
          sth<512>(Xb, mt * 16 + lg * 4 + q, col, f2bf(fmaxf(acc[mt][ntl][q] + bb, 0.f)));
    }
  }
  __syncthreads();
  // pe L3: K=256 (Xb) -> 256 + b3 + tesf -> Xb (both passes' accs held across barrier)
  {
    f32x4_t acc[2][2][2];   // [pass][mt][ntl] = 32 regs
    #pragma unroll
    for (int p = 0; p < 2; p++)
      #pragma unroll
      for (int mt = 0; mt < 2; mt++) { acc[p][mt][0] = 0.f; acc[p][mt][1] = 0.f; }
    for (int p = 0; p < 2; p++)
      mmW<8, 2, 2, 512>(pw3, 0, p * 8 + w * 2, 16, Xb, 0, lane, acc[p]);
    __syncthreads();
    #pragma unroll
    for (int p = 0; p < 2; p++)
      #pragma unroll
      for (int ntl = 0; ntl < 2; ntl++) {
        int col = (p * 8 + w * 2 + ntl) * 16 + lr;
        float bb = pe_b3[col] + tesf[col];
        #pragma unroll
        for (int mt = 0; mt < 2; mt++)
          #pragma unroll
          for (int q = 0; q < 4; q++)
            sth<512>(Xb, mt * 16 + lg * 4 + q, col, f2bf(acc[p][mt][ntl][q] + bb));
      }
  }
  __syncthreads();
  // 6 residual layers:
  //  A: X(K=256) @ W1 -> H (N=512; NT=32; 4 passes x NTW=2) | bar
  //  B: H(K=512) @ W2 -> += X (N=256; NT=16; 2 passes x NTW=2) | bar
  for (int l = 0; l < 6; l++) {
    const unsigned short* w1l = w1p + (size_t)l * 131072;
    const unsigned short* w2l = w2p + (size_t)l * 131072;
    for (int pass = 0; pass < 4; pass++) {
      f32x4_t accA[2][2];
      #pragma unroll
      for (int mt = 0; mt < 2; mt++) { accA[mt][0] = 0.f; accA[mt][1] = 0.f; }
      mmW<8, 2, 2, 512>(w1l, 0, pass * 8 + w * 2, 32, Xb, 0, lane, accA);
      #pragma unroll
      for (int ntl = 0; ntl < 2; ntl++) {
        int cl = (pass * 8 + w * 2 + ntl) * 16 + lr;
        float bb = lb1[l * 512 + cl];
        #pragma unroll
        for (int mt = 0; mt < 2; mt++)
          #pragma unroll
          for (int q = 0; q < 4; q++)
            sth<1024>(Hb, mt * 16 + lg * 4 + q, cl, f2bf(fmaxf(accA[mt][ntl][q] + bb, 0.f)));
      }
    }
    __syncthreads();
    for (int pass = 0; pass < 2; pass++) {
      f32x4_t accB[2][2];
      #pragma unroll
      for (int mt = 0; mt < 2; mt++) { accB[mt][0] = 0.f; accB[mt][1] = 0.f; }
      mmW<16, 2, 2, 1024>(w2l, 0, pass * 8 + w * 2, 16, Hb, 0, lane, accB);
      #pragma unroll
      for (int ntl = 0; ntl < 2; ntl++) {
        int col = (pass * 8 + w * 2 + ntl) * 16 + lr;
        float bb = lb2[l * 256 + col];
        #pragma unroll
        for (int mt = 0; mt < 2; mt++)
          #pragma unroll
          for (int q = 0; q < 4; q++) {
            int r = mt * 16 + lg * 4 + q;
            float xo = ldbf<512>(Xb, r, col);
            sth<512>(Xb, r, col, f2bf(xo + accB[mt][ntl][q] + bb));
          }
      }
    }
    __syncthreads();
  }
  // o1: X -> 256 relu -> Hb cols [0,256)  (2 passes)
  for (int pass = 0; pass < 2; pass++) {
    f32x4_t acc[2][2];
    #pragma unroll
    for (int mt = 0; mt < 2; mt++) { acc[mt][0] = 0.f; acc[mt][1] = 0.f; }
    mmW<8, 2, 2, 512>(o1p, 0, pass * 8 + w * 2, 16, Xb, 0, lane, acc);
    #pragma unroll
    for (int ntl = 0; ntl < 2; ntl++) {
      int col = (pass * 8 + w * 2 + ntl) * 16 + lr;
      float bb = ob1[col];
      #pragma unroll
      for (int mt = 0; mt < 2; mt++)
        #pragma unroll
        for (int q = 0; q < 4; q++)
          sth<1024>(Hb, mt * 16 + lg * 4 + q, col, f2bf(fmaxf(acc[mt][ntl][q] + bb, 0.f)));
    }
  }
  __syncthreads();
  // o2: K=256 (Hb[0:256)) -> 128 relu -> Hb cols [256,384)  (NT=8, single pass)
  {
    f32x4_t acc[2][2];
    #pragma unroll
    for (int mt = 0; mt < 2; mt++) { acc[mt][0] = 0.f; acc[mt][1] = 0.f; }
    mmW<8, 2, 2, 1024>(o2p, 0, w * 2, 8, Hb, 0, lane, acc);
    #pragma unroll
    for (int ntl = 0; ntl < 2; ntl++) {
      int col = (w * 2 + ntl) * 16 + lr;
      float bb = ob2[col];
      #pragma unroll
      for (int mt = 0; mt < 2; mt++)
        #pragma unroll
        for (int q = 0; q < 4; q++)
          sth<1024>(Hb, mt * 16 + lg * 4 + q, 256 + col, f2bf(fmaxf(acc[mt][ntl][q] + bb, 0.f)));
    }
  }
  __syncthreads();
  // o3: 128 -> 3
  if (t < 96) {
    int r = t / 3, cc = t % 3, grow = row0 + r;
    if (grow < M_PTS) {
      float acc = ob3[cc];
      for (int k = 0; k < 128; k++) acc += ldbf<1024>(Hb, r, 256 + k) * ow3[k * 3 + cc];
      pred[((size_t)bt * M_PTS + grow) * 3 + cc] = acc;
    }
  }
}

// ---------------- launch ----------------

extern "C" void kernel_launch(void* const* d_in, const int* in_sizes, int n_in,
                              void* d_out, int out_size, void* d_ws, size_t ws_size,
                              hipStream_t stream) {
  const float* noisy = (const float*)d_in[0];
  const int* tstep = (const int*)d_in[1];
  const float* cond = (const float*)d_in[2];
  const float* se_w1 = (const float*)d_in[3];  const float* se_b1 = (const float*)d_in[4];
  const float* se_w2 = (const float*)d_in[5];  const float* se_b2 = (const float*)d_in[6];
  const float* se_w3 = (const float*)d_in[7];  const float* se_b3 = (const float*)d_in[8];
  const float* sm_w1 = (const float*)d_in[9];  const float* sm_b1 = (const float*)d_in[10];
  const float* sm_w2 = (const float*)d_in[11]; const float* sm_b2 = (const float*)d_in[12];
  const float* pe_w1 = (const float*)d_in[13]; const float* pe_b1 = (const float*)d_in[14];
  const float* pe_w2 = (const float*)d_in[15]; const float* pe_b2 = (const float*)d_in[16];
  const float* pe_w3 = (const float*)d_in[17]; const float* pe_b3 = (const float*)d_in[18];
  const float* tp_w = (const float*)d_in[19];  const float* tp_b = (const float*)d_in[20];
  const float* sp_w = (const float*)d_in[21];  const float* sp_b = (const float*)d_in[22];
  const float* lw1 = (const float*)d_in[23];   const float* lb1 = (const float*)d_in[24];
  const float* lw2 = (const float*)d_in[25];   const float* lb2 = (const float*)d_in[26];
  const float* ow1 = (const float*)d_in[27];   const float* ob1 = (const float*)d_in[28];
  const float* ow2 = (const float*)d_in[29];   const float* ob2 = (const float*)d_in[30];
  const float* ow3 = (const float*)d_in[31];   const float* ob3 = (const float*)d_in[32];

  char* ws = (char*)d_ws;
  unsigned long long* key = (unsigned long long*)(ws + OFF_KEY);
  int* cnt = (int*)(ws + OFF_CNT);
  int* sum = (int*)(ws + OFF_SUM);
  int* sel = (int*)(ws + OFF_SEL);
  Aux* aux = (Aux*)(ws + OFF_AUX);
  float* down = (float*)(ws + OFF_DOWN);
  unsigned* genc = (unsigned*)(ws + OFF_GENC);
  float* tesf2 = (float*)(ws + OFF_TESF);
  unsigned short* psew2 = (unsigned short*)(ws + OFF_PSEW2);
  unsigned short* psew3 = (unsigned short*)(ws + OFF_PSEW3);
  unsigned short* ppew2 = (unsigned short*)(ws + OFF_PPEW2);
  unsigned short* ppew3 = (unsigned short*)(ws + OFF_PPEW3);
  unsigned short* pow1 = (unsigned short*)(ws + OFF_POW1);
  unsigned short* pow2 = (unsigned short*)(ws + OFF_POW2);
  unsigned short* plw1 = (unsigned short*)(ws + OFF_PLW1);
  unsigned short* plw2 = (unsigned short*)(ws + OFF_PLW2);
  int* scnt = (int*)(ws + OFF_SCNT);
  int* ktot = (int*)(ws + OFF_KTOT);

  float* pred = (float*)d_out;
  float* idxout = (float*)d_out + (size_t)2 * M_PTS * 3;

  // downsample: all 4 clouds in parallel
  k_init<<<(4 * TS) / 256, 256, 0, stream>>>(key, cnt, sum, sel, aux, genc);
  k_minmax<<<dim3(64, 4), 256, 0, stream>>>(noisy, cond, aux);
  k_build<<<dim3(469, 4), 256, 0, stream>>>(noisy, cond, aux, key, cnt, sum);
  k_reps<<<dim3(TS / 256, 4), 256, 0, stream>>>(key, cnt, sum, sel);
  k_sel_cnt<<<dim3(NSCH, 4), 256, 0, stream>>>(sel, scnt);
  k_sel_scan<<<4, 512, 0, stream>>>(scnt, ktot);
  k_sel_gather<<<dim3(NSCH, 4), 256, 0, stream>>>(sel, scnt, ktot, noisy, cond, down, idxout);

  // pack all MFMA weights in one dispatch
  k_pack_all<<<884, 256, 0, stream>>>(se_w2, se_w3, pe_w2, pe_w3, ow1, ow2, lw1, lw2,
                                      psew2, psew3, ppew2, ppew3, pow1, pow2, plw1, plw2);

  // style chain
  k_style2<<<dim3(NCHUNK, 2), 512, 0, stream>>>(down, se_w1, se_b1, psew2, se_b2,
                                                psew3, se_b3, genc);
  k_smt<<<2, 512, 0, stream>>>(genc, sm_w1, sm_b1, sm_w2, sm_b2,
                               tstep, tp_w, tp_b, sp_w, sp_b, tesf2);

  // fused network, both batches
  k_net<<<dim3(NCH32, 2), 256, 0, stream>>>(down, tesf2,
                                            pe_w1, pe_b1, ppew2, pe_b2, ppew3, pe_b3,
                                            plw1, lb1, plw2, lb2,
                                            pow1, ob1, pow2, ob2, ow3, ob3, pred);
}

// Round 14
// 623.617 us; speedup vs baseline: 2.1477x; 2.1477x over previous
//
#include <hip/hip_runtime.h>
#include <math.h>

#define N_PTS 120000
#define M_PTS 30000
#define NCHUNK 469               // style: 469 * 64 rows = 30016 (padded)
#define NCH32 938                // k_net: 938 * 32 rows = 30016
#define TS (1 << 17)
#define TSM (TS - 1)
#define SCH 256                  // select chunk
#define NSCH 469                 // ceil(120000/256)

typedef __attribute__((ext_vector_type(8))) short bf16x8_t;
typedef __attribute__((ext_vector_type(4))) float f32x4_t;

// ---------------- workspace layout (bytes) ----------------
#define OFF_KEY    0ull                   // 4*TS*8  = 4194304
#define OFF_CNT    4194304ull             // 4*TS*4  = 2097152
#define OFF_SUM    6291456ull             // 2097152
#define OFF_SEL    8388608ull             // 4*120000*4 = 1920000
#define OFF_AUX    10308608ull            // 256
#define OFF_DOWN   10308864ull            // 4*30000*3*4 = 1440000
#define OFF_GENC   11748864ull            // 2048
#define OFF_STYLE  11750912ull            // 2048
#define OFF_TESF   11752960ull            // 2048
#define OFF_PSEW2  11755008ull            // 16384
#define OFF_PSEW3  11771392ull            // 65536
#define OFF_PPEW2  11836928ull            // 65536
#define OFF_PPEW3  11902464ull            // 131072
#define OFF_POW1   12033536ull            // 131072
#define OFF_POW2   12164608ull            // 65536
#define OFF_PLW1   12230144ull            // 1572864
#define OFF_PLW2   13803008ull            // 1572864
#define OFF_SCNT   15375872ull            // 4*469*4 = 7504
#define OFF_KTOT   15383552ull            // 16
#define WS_NEED    15383568ull

struct Aux {
  unsigned mn_enc[3];
  unsigned mx_enc[3];
  unsigned pad[10];   // -> 64 B
};

__device__ __forceinline__ unsigned encf(float v) {
  unsigned u = __float_as_uint(v);
  return (u & 0x80000000u) ? ~u : (u | 0x80000000u);
}
__device__ __forceinline__ float decf(unsigned u) {
  unsigned v = (u & 0x80000000u) ? (u & 0x7fffffffu) : ~u;
  return __uint_as_float(v);
}
__device__ __forceinline__ unsigned short f2bf(float f) {
  unsigned u = __float_as_uint(f);
  u += 0x7fffu + ((u >> 16) & 1u);
  return (unsigned short)(u >> 16);
}
// XOR-swizzled address into a bf16 tile with row stride RS bytes
template <int RS>
__device__ __forceinline__ unsigned swzad(int r, int c) {
  return ((unsigned)(r * RS + c * 2)) ^ ((unsigned)(r & 7) << 4);
}
template <int RS>
__device__ __forceinline__ void sth(unsigned short* B, int r, int c, unsigned short v) {
  *(unsigned short*)((char*)B + swzad<RS>(r, c)) = v;
}
template <int RS>
__device__ __forceinline__ float ldbf(const unsigned short* B, int r, int c) {
  unsigned short u = *(const unsigned short*)((const char*)B + swzad<RS>(r, c));
  return __uint_as_float((unsigned)u << 16);
}

// ---------------- downsample kernels (4 clouds in parallel) ----------------

__global__ void k_init(unsigned long long* __restrict__ key, int* __restrict__ cnt,
                       int* __restrict__ sum, int* __restrict__ sel, Aux* aux,
                       unsigned* __restrict__ genc) {
  int i = blockIdx.x * blockDim.x + threadIdx.x;
  if (i < 4 * TS) { key[i] = 0ull; cnt[i] = 0; sum[i] = 0; }
  if (i < 4 * N_PTS) sel[i] = 0;
  if (i < 12) { aux[i / 3].mn_enc[i % 3] = 0xFFFFFFFFu; aux[i / 3].mx_enc[i % 3] = 0u; }
  if (i < 512) genc[i] = 0u;
}

__device__ __forceinline__ const float* cloud_ptr(const float* noisy, const float* cond, int c) {
  return ((c & 1) ? noisy : cond) + (size_t)(c >> 1) * N_PTS * 3;
}

__global__ void k_minmax(const float* __restrict__ noisy, const float* __restrict__ cond,
                         Aux* aux) {
  __shared__ unsigned smn[3], smx[3];
  int t = threadIdx.x, c = blockIdx.y;
  const float* pts = cloud_ptr(noisy, cond, c);
  if (t < 3) { smn[t] = 0xFFFFFFFFu; smx[t] = 0u; }
  __syncthreads();
  unsigned lmn[3] = {0xFFFFFFFFu, 0xFFFFFFFFu, 0xFFFFFFFFu};
  unsigned lmx[3] = {0u, 0u, 0u};
  for (int i = blockIdx.x * blockDim.x + t; i < N_PTS; i += gridDim.x * blockDim.x) {
    #pragma unroll
    for (int k = 0; k < 3; k++) {
      unsigned e = encf(pts[i * 3 + k]);
      lmn[k] = min(lmn[k], e);
      lmx[k] = max(lmx[k], e);
    }
  }
  #pragma unroll
  for (int k = 0; k < 3; k++) { atomicMin(&smn[k], lmn[k]); atomicMax(&smx[k], lmx[k]); }
  __syncthreads();
  if (t < 3) { atomicMin(&aux[c].mn_enc[t], smn[t]); atomicMax(&aux[c].mx_enc[t], smx[t]); }
}

// vs computed per block from aux encodings (k_vs folded in)
__global__ void k_build(const float* __restrict__ noisy, const float* __restrict__ cond,
                        const Aux* __restrict__ aux, unsigned long long* __restrict__ keyg,
                        int* __restrict__ cntg, int* __restrict__ sumg) {
  __shared__ float smn[3];
  __shared__ double svs;
  int i = blockIdx.x * blockDim.x + threadIdx.x;
  int c = blockIdx.y;
  if (threadIdx.x == 0) {
    double prod = 1.0;
    for (int k = 0; k < 3; k++) {
      float mnf = decf(aux[c].mn_enc[k]);
      float mxf = decf(aux[c].mx_enc[k]);
      smn[k] = mnf;
      double r = (double)mxf - (double)mnf;
      if (r < 1e-6) r = 1.0;
      prod *= r;
    }
    double vs = pow(prod / (double)M_PTS, 1.0 / 3.0) * 1.2;
    if (vs < 1e-6) vs = 0.001;
    svs = vs;
  }
  __syncthreads();
  if (i >= N_PTS) return;
  const float* pts = cloud_ptr(noisy, cond, c);
  unsigned long long* key = keyg + (size_t)c * TS;
  int* cnt = cntg + (size_t)c * TS;
  int* sum = sumg + (size_t)c * TS;
  double vs = svs;
  unsigned h = 0u;
  const unsigned mulc[3] = {73856093u, 19349663u, 83492791u};
  #pragma unroll
  for (int k = 0; k < 3; k++) {
    int vi = (int)floor(((double)pts[i * 3 + k] - (double)smn[k]) / vs);
    h ^= (unsigned)vi * mulc[k];
  }
  unsigned long long want = 0x100000000ull | (unsigned long long)h;
  unsigned slot = (h * 2654435761u) >> 15;   // top 17 bits
  for (;;) {
    unsigned long long cur = key[slot];
    if (cur == want) break;
    if (cur == 0ull) {
      unsigned long long prev = atomicCAS(&key[slot], 0ull, want);
      if (prev == 0ull || prev == want) break;
    }
    slot = (slot + 1) & TSM;
  }
  atomicAdd(&cnt[slot], 1);
  atomicAdd(&sum[slot], i);
}

__global__ void k_reps(const unsigned long long* __restrict__ keyg, const int* __restrict__ cntg,
                       const int* __restrict__ sumg, int* __restrict__ selg) {
  int s = blockIdx.x * blockDim.x + threadIdx.x;
  int c = blockIdx.y;
  if (s >= TS) return;
  if (keyg[(size_t)c * TS + s] != 0ull) {
    int rep = sumg[(size_t)c * TS + s] / cntg[(size_t)c * TS + s];
    selg[(size_t)c * N_PTS + rep] = 1;
  }
}

// ---- 3-phase parallel stable select ----
__global__ void k_sel_cnt(const int* __restrict__ selg, int* __restrict__ scnt) {
  __shared__ int ws[4];
  int c = blockIdx.y, chunk = blockIdx.x, t = threadIdx.x;
  int i = chunk * SCH + t;
  int v = (i < N_PTS) ? selg[(size_t)c * N_PTS + i] : 0;
  int lane = t & 63, wid = t >> 6;
  int s = v;
  for (int d = 32; d; d >>= 1) s += __shfl_down(s, d, 64);
  if (lane == 0) ws[wid] = s;
  __syncthreads();
  if (t == 0) scnt[c * NSCH + chunk] = ws[0] + ws[1] + ws[2] + ws[3];
}

__global__ void k_sel_scan(int* __restrict__ scnt, int* __restrict__ ktot) {
  __shared__ int buf[512];
  int c = blockIdx.x, t = threadIdx.x;
  int v = (t < NSCH) ? scnt[c * NSCH + t] : 0;
  buf[t] = v;
  __syncthreads();
  for (int d = 1; d < 512; d <<= 1) {
    int x = (t >= d) ? buf[t - d] : 0;
    __syncthreads();
    buf[t] += x;
    __syncthreads();
  }
  if (t < NSCH) scnt[c * NSCH + t] = buf[t] - v;   // exclusive
  if (t == NSCH - 1) ktot[c] = buf[t];
}

__global__ void k_sel_gather(const int* __restrict__ selg, const int* __restrict__ scnt,
                             const int* __restrict__ ktot,
                             const float* __restrict__ noisy, const float* __restrict__ cond,
                             float* __restrict__ downg, float* __restrict__ idxbase) {
  __shared__ int wbase[4];
  int c = blockIdx.y, chunk = blockIdx.x, t = threadIdx.x;
  int i = chunk * SCH + t;
  int v = (i < N_PTS) ? selg[(size_t)c * N_PTS + i] : 0;
  int lane = t & 63, wid = t >> 6;
  int incl = v;
  for (int d = 1; d < 64; d <<= 1) {
    int x = __shfl_up(incl, d, 64);
    if (lane >= d) incl += x;
  }
  if (lane == 63) wbase[wid] = incl;
  __syncthreads();
  int wb = 0;
  for (int k = 0; k < wid; k++) wb += wbase[k];
  int selBefore = scnt[c * NSCH + chunk] + wb + incl - v;
  if (i >= N_PTS) return;
  int slot = v ? selBefore : (ktot[c] + i - selBefore);
  if (slot < M_PTS) {
    const float* pts = cloud_ptr(noisy, cond, c);
    float* down = downg + (size_t)c * M_PTS * 3;
    down[slot * 3 + 0] = pts[i * 3 + 0];
    down[slot * 3 + 1] = pts[i * 3 + 1];
    down[slot * 3 + 2] = pts[i * 3 + 2];
    if (c & 1) idxbase[(size_t)(c >> 1) * M_PTS + slot] = (float)i;
  }
}

// ---------------- fused weight packing into MFMA B-frag order ----------------
__device__ __forceinline__ void pack_one(const float* __restrict__ W,
                                         unsigned short* __restrict__ dst,
                                         int KS, int NT, int idx) {
  int lane = idx & 63;
  int rest = idx >> 6;
  int nt = rest % NT; rest /= NT;
  int ks = rest % KS;
  int l = rest / KS;
  int N = NT * 16, K = KS * 32;
  const float* src = W + (size_t)l * K * N;
  int cc = nt * 16 + (lane & 15);
  int k0 = ks * 32 + ((lane >> 4) << 3);
  unsigned short* d = dst + (size_t)idx * 8;
  #pragma unroll
  for (int j = 0; j < 8; j++) d[j] = f2bf(src[(size_t)(k0 + j) * N + cc]);
}

__global__ void k_pack_all(
    const float* __restrict__ se_w2, const float* __restrict__ se_w3,
    const float* __restrict__ pe_w2, const float* __restrict__ pe_w3,
    const float* __restrict__ ow1, const float* __restrict__ ow2,
    const float* __restrict__ lw1, const float* __restrict__ lw2,
    unsigned short* __restrict__ psew2, unsigned short* __restrict__ psew3,
    unsigned short* __restrict__ ppew2, unsigned short* __restrict__ ppew3,
    unsigned short* __restrict__ pow1, unsigned short* __restrict__ pow2,
    unsigned short* __restrict__ plw1, unsigned short* __restrict__ plw2) {
  int blk = blockIdx.x;
  const float* W; unsigned short* D; int KS, NT, base;
  if (blk < 4)        { W = se_w2; D = psew2; KS = 2;  NT = 8;  base = 0; }
  else if (blk < 20)  { W = se_w3; D = psew3; KS = 4;  NT = 16; base = 4; }
  else if (blk < 36)  { W = pe_w2; D = ppew2; KS = 4;  NT = 16; base = 20; }
  else if (blk < 68)  { W = pe_w3; D = ppew3; KS = 8;  NT = 16; base = 36; }
  else if (blk < 100) { W = ow1;   D = pow1;  KS = 8;  NT = 16; base = 68; }
  else if (blk < 116) { W = ow2;   D = pow2;  KS = 8;  NT = 8;  base = 100; }
  else if (blk < 500) { W = lw1;   D = plw1;  KS = 8;  NT = 32; base = 116; }
  else                { W = lw2;   D = plw2;  KS = 16; NT = 16; base = 500; }
  pack_one(W, D, KS, NT, (blk - base) * 256 + threadIdx.x);
}

// ---------------- MFMA core (no prefetch, NTW<=2 register-proven) ----------------
template <int KS, int NTW, int MT, int RS>
__device__ __forceinline__ void mmW(const unsigned short* __restrict__ Bp,
                                    int kt0, int nt0, int NT,
                                    const unsigned short* __restrict__ A, int acb,
                                    int lane, f32x4_t (&acc)[MT][NTW]) {
  const int lr = lane & 15, lg = lane >> 4;
  #pragma unroll
  for (int ks = 0; ks < KS; ks++) {
    bf16x8_t af[MT];
    #pragma unroll
    for (int mt = 0; mt < MT; mt++)
      af[mt] = *(const bf16x8_t*)((const char*)A + swzad<RS>(mt * 16 + lr, acb + ks * 32 + lg * 8));
    #pragma unroll
    for (int n = 0; n < NTW; n++) {
      bf16x8_t b = *(const bf16x8_t*)(Bp + ((size_t)((kt0 + ks) * NT + nt0 + n) * 64 + lane) * 8);
      #pragma unroll
      for (int mt = 0; mt < MT; mt++)
        acc[mt][n] = __builtin_amdgcn_mfma_f32_16x16x32_bf16(af[mt], b, acc[mt][n], 0, 0, 0);
    }
  }
}

// ---------------- style encoder (per-point MLP + max pool) ----------------
__global__ __launch_bounds__(512, 2) void k_style2(
    const float* __restrict__ downg,
    const float* __restrict__ se_w1, const float* __restrict__ se_b1,
    const unsigned short* __restrict__ w2p, const float* __restrict__ se_b2,
    const unsigned short* __restrict__ w3p, const float* __restrict__ se_b3,
    unsigned* __restrict__ genc) {
  __shared__ __attribute__((aligned(16))) unsigned short Hs[64 * 256];
  const int t = threadIdx.x, lane = t & 63, w = t >> 6;
  const int lr = lane & 15, lg = lane >> 4;
  const int bt = blockIdx.y;
  const int row0 = blockIdx.x * 64;
  const float* downC = downg + (size_t)(bt << 1) * M_PTS * 3;
  {
    int r = t & 63, grow = row0 + r;
    float px = 0.f, py = 0.f, pz = 0.f;
    if (grow < M_PTS) { px = downC[grow * 3]; py = downC[grow * 3 + 1]; pz = downC[grow * 3 + 2]; }
    int c0 = (t >> 6) * 8;
    for (int i = 0; i < 8; i++) {
      int c = c0 + i;
      float v = fmaxf(se_b1[c] + px * se_w1[c] + py * se_w1[64 + c] + pz * se_w1[128 + c], 0.f);
      sth<512>(Hs, r, c, f2bf(v));
    }
  }
  __syncthreads();
  {
    f32x4_t acc[4][1];
    #pragma unroll
    for (int mt = 0; mt < 4; mt++) acc[mt][0] = 0.f;
    mmW<2, 1, 4, 512>(w2p, 0, w, 8, Hs, 0, lane, acc);
    int col = w * 16 + lr;
    float bb = se_b2[col];
    #pragma unroll
    for (int mt = 0; mt < 4; mt++)
      #pragma unroll
      for (int q = 0; q < 4; q++)
        sth<512>(Hs, mt * 16 + lg * 4 + q, 128 + col, f2bf(fmaxf(acc[mt][0][q] + bb, 0.f)));
  }
  __syncthreads();
  {
    f32x4_t acc[4][2];
    #pragma unroll
    for (int mt = 0; mt < 4; mt++) { acc[mt][0] = 0.f; acc[mt][1] = 0.f; }
    mmW<4, 2, 4, 512>(w3p, 0, w * 2, 16, Hs, 128, lane, acc);
    #pragma unroll
    for (int ntl = 0; ntl < 2; ntl++) {
      int col = (w * 2 + ntl) * 16 + lr;
      float bb = se_b3[col];
      float m = -3.4e38f;
      #pragma unroll
      for (int mt = 0; mt < 4; mt++)
        #pragma unroll
        for (int q = 0; q < 4; q++) {
          int grow = row0 + mt * 16 + lg * 4 + q;
          float v = acc[mt][ntl][q] + bb;
          if (grow < M_PTS) m = fmaxf(m, v);
        }
      m = fmaxf(m, __shfl_xor(m, 16, 64));
      m = fmaxf(m, __shfl_xor(m, 32, 64));
      if (lg == 0) atomicMax(&genc[bt * 256 + col], encf(m));
    }
  }
}

// style MLP + time/style projection, fused; grid 2, 512 thr
__global__ void k_smt(const unsigned* __restrict__ genc,
                      const float* __restrict__ w1, const float* __restrict__ b1,
                      const float* __restrict__ w2, const float* __restrict__ b2,
                      const int* __restrict__ tstep,
                      const float* __restrict__ tpw, const float* __restrict__ tpb,
                      const float* __restrict__ spw, const float* __restrict__ spb,
                      float* __restrict__ tesf2) {
  __shared__ float g[256], s1[512], st[256], te[128];
  int t = threadIdx.x, b = blockIdx.x;
  if (t < 256) g[t] = decf(genc[b * 256 + t]);
  __syncthreads();
  float h = b1[t];
  for (int k = 0; k < 256; k++) h += g[k] * w1[k * 512 + t];
  s1[t] = fmaxf(h, 0.f);
  __syncthreads();
  if (t < 256) {
    float o = b2[t];
    for (int k = 0; k < 512; k++) o += s1[k] * w2[k * 256 + t];
    st[t] = fmaxf(o, 0.f);
  }
  if (t < 64) {
    const float cfr = (float)(-9.210340371976184 / 63.0);
    float fr = expf((float)t * cfr);
    float ang = (float)tstep[b] * fr;
    te[t] = sinf(ang);
    te[64 + t] = cosf(ang);
  }
  __syncthreads();
  if (t < 256) {
    float v = tpb[t];
    for (int k = 0; k < 128; k++) v += te[k] * tpw[k * 256 + t];
    float v2 = spb[t];
    for (int k = 0; k < 256; k++) v2 += st[k] * spw[k * 256 + t];
    tesf2[b * 256 + t] = v + v2;
  }
}

// ---------------- fused per-point network: pe -> 6x residual -> out head ----------------
// 32 rows/block, 4 waves (MT=2, NTW=2, sequential passes kept un-unrolled), 48KB LDS.
// launch_bounds(256,2) -> 128 VGPR cap; no runtime-indexed acc arrays (rule #20).
__global__ __launch_bounds__(256, 2) void k_net(
    const float* __restrict__ downg, const float* __restrict__ tesf2,
    const float* __restrict__ pe_w1, const float* __restrict__ pe_b1,
    const unsigned short* __restrict__ pw2, const float* __restrict__ pe_b2,
    const unsigned short* __restrict__ pw3, const float* __restrict__ pe_b3,
    const unsigned short* __restrict__ w1p, const float* __restrict__ lb1,
    const unsigned short* __restrict__ w2p, const float* __restrict__ lb2,
    const unsigned short* __restrict__ o1p, const float* __restrict__ ob1,
    const unsigned short* __restrict__ o2p, const float* __restrict__ ob2,
    const float* __restrict__ ow3, const float* __restrict__ ob3,
    float* __restrict__ pred) {
  __shared__ __attribute__((aligned(16))) unsigned short Xb[32 * 256];  // 16 KB
  __shared__ __attribute__((aligned(16))) unsigned short Hb[32 * 512];  // 32 KB
  const int t = threadIdx.x, lane = t & 63, w = t >> 6;   // 4 waves
  const int lr = lane & 15, lg = lane >> 4;
  const int bt = blockIdx.y;
  const int row0 = blockIdx.x * 32;
  const float* dn = downg + (size_t)((bt << 1) | 1) * M_PTS * 3;
  const float* tesf = tesf2 + bt * 256;

  // pe L1: 3 -> 128 relu -> Hb cols [0,128)
  {
    int r = t & 31, grow = row0 + r;
    float px = 0.f, py = 0.f, pz = 0.f;
    if (grow < M_PTS) { px = dn[grow * 3]; py = dn[grow * 3 + 1]; pz = dn[grow * 3 + 2]; }
    int c0 = (t >> 5) * 16;
    for (int i = 0; i < 16; i++) {
      int c = c0 + i;
      float v = fmaxf(pe_b1[c] + px * pe_w1[c] + py * pe_w1[128 + c] + pz * pe_w1[256 + c], 0.f);
      sth<1024>(Hb, r, c, f2bf(v));
    }
  }
  __syncthreads();
  // pe L2: K=128 (Hb) -> 256 relu -> Xb  (NT=16, 2 sequential passes x NTW=2)
  #pragma unroll 1
  for (int pass = 0; pass < 2; pass++) {
    f32x4_t acc[2][2];
    #pragma unroll
    for (int mt = 0; mt < 2; mt++) { acc[mt][0] = 0.f; acc[mt][1] = 0.f; }
    mmW<4, 2, 2, 1024>(pw2, 0, pass * 8 + w * 2, 16, Hb, 0, lane, acc);
    #pragma unroll
    for (int ntl = 0; ntl < 2; ntl++) {
      int col = (pass * 8 + w * 2 + ntl) * 16 + lr;
      float bb = pe_b2[col];
      #pragma unroll
      for (int mt = 0; mt < 2; mt++)
        #pragma unroll
        for (int q = 0; q < 4; q++)
          sth<512>(Xb, mt * 16 + lg * 4 + q, col, f2bf(fmaxf(acc[mt][ntl][q] + bb, 0.f)));
    }
  }
  __syncthreads();
  // pe L3: K=256 (Xb) -> 256 + b3 + tesf -> Xb
  // NAMED acc arrays, explicit sequential calls (rule #20: no runtime-indexed acc).
  {
    f32x4_t accP0[2][2], accP1[2][2];
    #pragma unroll
    for (int mt = 0; mt < 2; mt++) {
      accP0[mt][0] = 0.f; accP0[mt][1] = 0.f;
      accP1[mt][0] = 0.f; accP1[mt][1] = 0.f;
    }
    mmW<8, 2, 2, 512>(pw3, 0, 0 + w * 2, 16, Xb, 0, lane, accP0);
    mmW<8, 2, 2, 512>(pw3, 0, 8 + w * 2, 16, Xb, 0, lane, accP1);
    __syncthreads();
    #pragma unroll
    for (int ntl = 0; ntl < 2; ntl++) {
      int col0 = (w * 2 + ntl) * 16 + lr;
      int col1 = (8 * 16) + col0;
      float bb0 = pe_b3[col0] + tesf[col0];
      float bb1 = pe_b3[col1] + tesf[col1];
      #pragma unroll
      for (int mt = 0; mt < 2; mt++)
        #pragma unroll
        for (int q = 0; q < 4; q++) {
          int r = mt * 16 + lg * 4 + q;
          sth<512>(Xb, r, col0, f2bf(accP0[mt][ntl][q] + bb0));
          sth<512>(Xb, r, col1, f2bf(accP1[mt][ntl][q] + bb1));
        }
    }
  }
  __syncthreads();
  // 6 residual layers:
  //  A: X(K=256) @ W1 -> H (N=512; NT=32; 4 sequential passes x NTW=2) | bar
  //  B: H(K=512) @ W2 -> += X (N=256; NT=16; 2 sequential passes x NTW=2) | bar
  for (int l = 0; l < 6; l++) {
    const unsigned short* w1l = w1p + (size_t)l * 131072;
    const unsigned short* w2l = w2p + (size_t)l * 131072;
    #pragma unroll 1
    for (int pass = 0; pass < 4; pass++) {
      f32x4_t accA[2][2];
      #pragma unroll
      for (int mt = 0; mt < 2; mt++) { accA[mt][0] = 0.f; accA[mt][1] = 0.f; }
      mmW<8, 2, 2, 512>(w1l, 0, pass * 8 + w * 2, 32, Xb, 0, lane, accA);
      #pragma unroll
      for (int ntl = 0; ntl < 2; ntl++) {
        int cl = (pass * 8 + w * 2 + ntl) * 16 + lr;
        float bb = lb1[l * 512 + cl];
        #pragma unroll
        for (int mt = 0; mt < 2; mt++)
          #pragma unroll
          for (int q = 0; q < 4; q++)
            sth<1024>(Hb, mt * 16 + lg * 4 + q, cl, f2bf(fmaxf(accA[mt][ntl][q] + bb, 0.f)));
      }
    }
    __syncthreads();
    #pragma unroll 1
    for (int pass = 0; pass < 2; pass++) {
      f32x4_t accB[2][2];
      #pragma unroll
      for (int mt = 0; mt < 2; mt++) { accB[mt][0] = 0.f; accB[mt][1] = 0.f; }
      mmW<16, 2, 2, 1024>(w2l, 0, pass * 8 + w * 2, 16, Hb, 0, lane, accB);
      #pragma unroll
      for (int ntl = 0; ntl < 2; ntl++) {
        int col = (pass * 8 + w * 2 + ntl) * 16 + lr;
        float bb = lb2[l * 256 + col];
        #pragma unroll
        for (int mt = 0; mt < 2; mt++)
          #pragma unroll
          for (int q = 0; q < 4; q++) {
            int r = mt * 16 + lg * 4 + q;
            float xo = ldbf<512>(Xb, r, col);
            sth<512>(Xb, r, col, f2bf(xo + accB[mt][ntl][q] + bb));
          }
      }
    }
    __syncthreads();
  }
  // o1: X -> 256 relu -> Hb cols [0,256)  (2 sequential passes)
  #pragma unroll 1
  for (int pass = 0; pass < 2; pass++) {
    f32x4_t acc[2][2];
    #pragma unroll
    for (int mt = 0; mt < 2; mt++) { acc[mt][0] = 0.f; acc[mt][1] = 0.f; }
    mmW<8, 2, 2, 512>(o1p, 0, pass * 8 + w * 2, 16, Xb, 0, lane, acc);
    #pragma unroll
    for (int ntl = 0; ntl < 2; ntl++) {
      int col = (pass * 8 + w * 2 + ntl) * 16 + lr;
      float bb = ob1[col];
      #pragma unroll
      for (int mt = 0; mt < 2; mt++)
        #pragma unroll
        for (int q = 0; q < 4; q++)
          sth<1024>(Hb, mt * 16 + lg * 4 + q, col, f2bf(fmaxf(acc[mt][ntl][q] + bb, 0.f)));
    }
  }
  __syncthreads();
  // o2: K=256 (Hb[0:256)) -> 128 relu -> Hb cols [256,384)  (NT=8, single pass)
  {
    f32x4_t acc[2][2];
    #pragma unroll
    for (int mt = 0; mt < 2; mt++) { acc[mt][0] = 0.f; acc[mt][1] = 0.f; }
    mmW<8, 2, 2, 1024>(o2p, 0, w * 2, 8, Hb, 0, lane, acc);
    #pragma unroll
    for (int ntl = 0; ntl < 2; ntl++) {
      int col = (w * 2 + ntl) * 16 + lr;
      float bb = ob2[col];
      #pragma unroll
      for (int mt = 0; mt < 2; mt++)
        #pragma unroll
        for (int q = 0; q < 4; q++)
          sth<1024>(Hb, mt * 16 + lg * 4 + q, 256 + col, f2bf(fmaxf(acc[mt][ntl][q] + bb, 0.f)));
    }
  }
  __syncthreads();
  // o3: 128 -> 3
  if (t < 96) {
    int r = t / 3, cc = t % 3, grow = row0 + r;
    if (grow < M_PTS) {
      float acc = ob3[cc];
      for (int k = 0; k < 128; k++) acc += ldbf<1024>(Hb, r, 256 + k) * ow3[k * 3 + cc];
      pred[((size_t)bt * M_PTS + grow) * 3 + cc] = acc;
    }
  }
}

// ---------------- launch ----------------

extern "C" void kernel_launch(void* const* d_in, const int* in_sizes, int n_in,
                              void* d_out, int out_size, void* d_ws, size_t ws_size,
                              hipStream_t stream) {
  const float* noisy = (const float*)d_in[0];
  const int* tstep = (const int*)d_in[1];
  const float* cond = (const float*)d_in[2];
  const float* se_w1 = (const float*)d_in[3];  const float* se_b1 = (const float*)d_in[4];
  const float* se_w2 = (const float*)d_in[5];  const float* se_b2 = (const float*)d_in[6];
  const float* se_w3 = (const float*)d_in[7];  const float* se_b3 = (const float*)d_in[8];
  const float* sm_w1 = (const float*)d_in[9];  const float* sm_b1 = (const float*)d_in[10];
  const float* sm_w2 = (const float*)d_in[11]; const float* sm_b2 = (const float*)d_in[12];
  const float* pe_w1 = (const float*)d_in[13]; const float* pe_b1 = (const float*)d_in[14];
  const float* pe_w2 = (const float*)d_in[15]; const float* pe_b2 = (const float*)d_in[16];
  const float* pe_w3 = (const float*)d_in[17]; const float* pe_b3 = (const float*)d_in[18];
  const float* tp_w = (const float*)d_in[19];  const float* tp_b = (const float*)d_in[20];
  const float* sp_w = (const float*)d_in[21];  const float* sp_b = (const float*)d_in[22];
  const float* lw1 = (const float*)d_in[23];   const float* lb1 = (const float*)d_in[24];
  const float* lw2 = (const float*)d_in[25];   const float* lb2 = (const float*)d_in[26];
  const float* ow1 = (const float*)d_in[27];   const float* ob1 = (const float*)d_in[28];
  const float* ow2 = (const float*)d_in[29];   const float* ob2 = (const float*)d_in[30];
  const float* ow3 = (const float*)d_in[31];   const float* ob3 = (const float*)d_in[32];

  char* ws = (char*)d_ws;
  unsigned long long* key = (unsigned long long*)(ws + OFF_KEY);
  int* cnt = (int*)(ws + OFF_CNT);
  int* sum = (int*)(ws + OFF_SUM);
  int* sel = (int*)(ws + OFF_SEL);
  Aux* aux = (Aux*)(ws + OFF_AUX);
  float* down = (float*)(ws + OFF_DOWN);
  unsigned* genc = (unsigned*)(ws + OFF_GENC);
  float* tesf2 = (float*)(ws + OFF_TESF);
  unsigned short* psew2 = (unsigned short*)(ws + OFF_PSEW2);
  unsigned short* psew3 = (unsigned short*)(ws + OFF_PSEW3);
  unsigned short* ppew2 = (unsigned short*)(ws + OFF_PPEW2);
  unsigned short* ppew3 = (unsigned short*)(ws + OFF_PPEW3);
  unsigned short* pow1 = (unsigned short*)(ws + OFF_POW1);
  unsigned short* pow2 = (unsigned short*)(ws + OFF_POW2);
  unsigned short* plw1 = (unsigned short*)(ws + OFF_PLW1);
  unsigned short* plw2 = (unsigned short*)(ws + OFF_PLW2);
  int* scnt = (int*)(ws + OFF_SCNT);
  int* ktot = (int*)(ws + OFF_KTOT);

  float* pred = (float*)d_out;
  float* idxout = (float*)d_out + (size_t)2 * M_PTS * 3;

  // downsample: all 4 clouds in parallel
  k_init<<<(4 * TS) / 256, 256, 0, stream>>>(key, cnt, sum, sel, aux, genc);
  k_minmax<<<dim3(64, 4), 256, 0, stream>>>(noisy, cond, aux);
  k_build<<<dim3(469, 4), 256, 0, stream>>>(noisy, cond, aux, key, cnt, sum);
  k_reps<<<dim3(TS / 256, 4), 256, 0, stream>>>(key, cnt, sum, sel);
  k_sel_cnt<<<dim3(NSCH, 4), 256, 0, stream>>>(sel, scnt);
  k_sel_scan<<<4, 512, 0, stream>>>(scnt, ktot);
  k_sel_gather<<<dim3(NSCH, 4), 256, 0, stream>>>(sel, scnt, ktot, noisy, cond, down, idxout);

  // pack all MFMA weights in one dispatch
  k_pack_all<<<884, 256, 0, stream>>>(se_w2, se_w3, pe_w2, pe_w3, ow1, ow2, lw1, lw2,
                                      psew2, psew3, ppew2, ppew3, pow1, pow2, plw1, plw2);

  // style chain
  k_style2<<<dim3(NCHUNK, 2), 512, 0, stream>>>(down, se_w1, se_b1, psew2, se_b2,
                                                psew3, se_b3, genc);
  k_smt<<<2, 512, 0, stream>>>(genc, sm_w1, sm_b1, sm_w2, sm_b2,
                               tstep, tp_w, tp_b, sp_w, sp_b, tesf2);

  // fused network, both batches
  k_net<<<dim3(NCH32, 2), 256, 0, stream>>>(down, tesf2,
                                            pe_w1, pe_b1, ppew2, pe_b2, ppew3, pe_b3,
                                            plw1, lb1, plw2, lb2,
                                            pow1, ob1, pow2, ob2, ow3, ob3, pred);
}